// Round 6
// baseline (303.546 us; speedup 1.0000x reference)
//
#include <hip/hip_runtime.h>
#include <stdint.h>

// Fixed 8x8x8 grid complex: nV=512, nE=2863, nT=4410, nTet=2058, nS=9843.
// Dim-1 pairs via COHOMOLOGY (coboundary delta_1) + clearing of MST edges:
// rows = edges (reverse filtration order), bits = triangles (reverse order).
// Negative (MST) edges' rows would reduce to zero -> cleared upfront.
#define MAX_E 3072
#define MAX_T 4608
#define MAX_V 1024
#define TW    72     // u64 words per row >= ceil(nT/64); 2 words/lane, lanes 0..35
#define INF_I 0x7fffffff
#define TBLK  18     // ceil(MAX_T/256)
#define RB_E  12     // edge-rank blocks
#define RB_T  18     // tri-rank blocks
#define RB_C  24     // clear blocks

__device__ int   g_erank[MAX_E];             // edge local idx -> rank (f desc, idx asc)
__device__ float g_ef[MAX_E];                // f by edge rank
__device__ int   g_trank[MAX_T];             // tri local idx -> rank
__device__ float g_tf[MAX_T];                // f by tri rank
__device__ __attribute__((aligned(16))) unsigned long long g_rows[(size_t)MAX_E * TW];
__device__ int   g_clr[MAX_E];               // row rr -> 1 if cleared (MST edge)
__device__ float g_loss0;

// sd is sorted (verts, edges, tris, tets): first index with dim > d.
__device__ __forceinline__ int ub_dim(const int* __restrict__ sd, int nS, int d) {
  int lo = 0, hi = nS;
  while (lo < hi) { int mid = (lo + hi) >> 1; if (sd[mid] <= d) lo = mid + 1; else hi = mid; }
  return lo;
}

// Fused: rank edges (blocks [0,RB_E)), rank tris ([RB_E,RB_E+RB_T)), clear
// g_rows/g_clr (rest). Rank blocks recompute f directly from beta (cached
// loads) into LDS -- no dependency on any prior kernel.
__global__ void __launch_bounds__(256) k_rankprep(const float* __restrict__ beta,
                                                  const int* __restrict__ sv,
                                                  const int* __restrict__ sd,
                                                  int nV, int nS) {
  int b = blockIdx.x, tid = threadIdx.x;
  if (b >= RB_E + RB_T) {
    size_t i = (size_t)(b - RB_E - RB_T) * 256 + tid;
    size_t stride = (size_t)RB_C * 256;
    for (size_t k = i; k < (size_t)MAX_E * TW; k += stride) g_rows[k] = 0ull;
    for (size_t k = i; k < MAX_E; k += stride) g_clr[k] = 0;
    return;
  }
  __shared__ float sf[MAX_T];
  int nE = ub_dim(sd, nS, 1) - nV;
  if (b < RB_E) {
    for (int j = tid; j < nE; j += 256) {
      const int* p = &sv[(size_t)(nV + j) * 4];
      sf[j] = fminf(beta[p[0]], beta[p[1]]);
    }
    __syncthreads();
    int i = b * 256 + tid;
    if (i >= nE) return;
    float fi = sf[i];
    int r = 0;
    for (int j = 0; j < nE; ++j) {
      float fj = sf[j];
      r += (fj > fi) || (fj == fi && j < i);
    }
    g_erank[i] = r;
    g_ef[r] = fi;
  } else {
    int nT = ub_dim(sd, nS, 2) - nV - nE;
    int base = nV + nE;
    for (int j = tid; j < nT; j += 256) {
      const int* p = &sv[(size_t)(base + j) * 4];
      sf[j] = fminf(fminf(beta[p[0]], beta[p[1]]), beta[p[2]]);
    }
    __syncthreads();
    int i = (b - RB_E) * 256 + tid;
    if (i >= nT) return;
    float fi = sf[i];
    int r = 0;
    for (int j = 0; j < nT; ++j) {
      float fj = sf[j];
      r += (fj > fi) || (fj == fi && j < i);
    }
    g_trank[i] = r;
    g_tf[r] = fi;
  }
}

// Fused: block 0 = Boruvka UF (loss0 + clearing marks); blocks 1.. = scatter
// coboundary rows. Disjoint outputs (g_clr/g_loss0 vs g_rows).
__global__ void __launch_bounds__(256) k_ufsc(const float* __restrict__ beta,
                                              const int* __restrict__ sv,
                                              const int* __restrict__ bf,
                                              const int* __restrict__ sd,
                                              int nV, int nS) {
  __shared__ int par[MAX_V];
  __shared__ unsigned long long cand[MAX_V];
  __shared__ int hookTo[MAX_V];
  __shared__ int eu[MAX_E], ev2[MAX_E];
  __shared__ float efv[MAX_E];
  __shared__ unsigned int ekey[MAX_E];
  __shared__ int era[MAX_E];
  __shared__ unsigned short alive[2][MAX_E];
  __shared__ int nNext;
  __shared__ float aS[4], aM[4], aW[4];
  int tid = threadIdx.x;
  int nE = ub_dim(sd, nS, 1) - nV;

  if (blockIdx.x != 0) {
    // ---- scatter role: build coboundary rows ----
    int nT = ub_dim(sd, nS, 2) - nV - nE;
    int t = (blockIdx.x - 1) * 256 + tid;
    if (t >= nT) return;
    int lpos = nT - 1 - g_trank[t];
    size_t base = (size_t)2 * nE + (size_t)3 * t;
    unsigned long long bit = 1ull << (lpos & 63);
    int word = lpos >> 6;
    for (int j = 0; j < 3; ++j) {
      int e = bf[base + j] - nV;
      int rr = nE - 1 - g_erank[e];
      atomicOr(&g_rows[(size_t)rr * TW + word], bit);
    }
    return;
  }

  // ---- UF role: loss0 = sum_v f(v) - max_v f(v) - W(canonical max ST).
  // Boruvka with STRICT keys (f desc, idx asc) == Kruskal's negative edge set;
  // alive-list compaction: only cross edges survive to the next phase.
  for (int v = tid; v < nV; v += 256) par[v] = v;
  for (int e = tid; e < nE; e += 256) {
    int u = sv[(size_t)(nV + e) * 4];
    int v = sv[(size_t)(nV + e) * 4 + 1];
    eu[e] = u; ev2[e] = v;
    float fe = fminf(beta[u], beta[v]);
    efv[e] = fe;
    era[e] = g_erank[e];
    unsigned int b = __float_as_uint(fe);
    ekey[e] = (b & 0x80000000u) ? ~b : (b | 0x80000000u);  // orderable
    alive[0][e] = (unsigned short)e;
  }
  float s = 0.f, m = -3.0e38f;
  for (int v = tid; v < nV; v += 256) { float fv = beta[v]; s += fv; m = fmaxf(m, fv); }
  float W = 0.f;
  int nAlive = nE, cur = 0;
  __syncthreads();
  for (int phase = 0; phase < 20 && nAlive > 0; ++phase) {
    for (int v = tid; v < nV; v += 256) cand[v] = 0ull;
    if (tid == 0) nNext = 0;
    __syncthreads();
    for (int i = tid; i < nAlive; i += 256) {
      int e = alive[cur][i];
      int ra = eu[e];  while (par[ra] != ra) ra = par[ra];
      int rb = ev2[e]; while (par[rb] != rb) rb = par[rb];
      if (ra != rb) {
        int q = atomicAdd(&nNext, 1);
        alive[cur ^ 1][q] = (unsigned short)e;
        // key: larger f wins; tie -> SMALLER edge idx wins (canonical order)
        unsigned long long key = ((unsigned long long)ekey[e] << 32)
                               | (unsigned long long)(0xffffffffu - (unsigned)e);
        atomicMax(&cand[ra], key);
        atomicMax(&cand[rb], key);
      }
    }
    __syncthreads();
    for (int v = tid; v < nV; v += 256) {
      int t = -1;
      unsigned long long cv = cand[v];
      if (par[v] == v && cv) {
        int e = (int)(0xffffffffu - (unsigned)(cv & 0xffffffffu));
        int ra = eu[e];  while (par[ra] != ra) ra = par[ra];
        int rb = ev2[e]; while (par[rb] != rb) rb = par[rb];
        int other = (ra == v) ? rb : ra;
        if (cand[other] != cv || v < other) t = other;  // break 2-cycles
      }
      hookTo[v] = t;
    }
    __syncthreads();
    for (int v = tid; v < nV; v += 256) {
      int t = hookTo[v];
      if (t >= 0) {
        par[v] = t;
        int e = (int)(0xffffffffu - (unsigned)(cand[v] & 0xffffffffu));
        W += efv[e];
        g_clr[nE - 1 - era[e]] = 1;          // negative edge -> cleared row
      }
    }
    __syncthreads();
    for (int it = 0; it < 5; ++it) {
      for (int v = tid; v < nV; v += 256) { int p = par[v]; int gp = par[p]; if (p != gp) par[v] = gp; }
      __syncthreads();
    }
    nAlive = nNext;
    cur ^= 1;
    __syncthreads();                          // nNext read-before-reset fence
  }
  int lane = tid & 63, wave = tid >> 6;
  #pragma unroll
  for (int off = 32; off; off >>= 1) {
    s += __shfl_xor(s, off, 64);
    m = fmaxf(m, __shfl_xor(m, off, 64));
    W += __shfl_xor(W, off, 64);
  }
  if (lane == 0) { aS[wave] = s; aM[wave] = m; aW[wave] = W; }
  __syncthreads();
  if (tid == 0) {
    float S = 0.f, M = -3.0e38f, WW = 0.f;
    for (int i = 0; i < 4; ++i) { S += aS[i]; M = fmaxf(M, aM[i]); WW += aW[i]; }
    g_loss0 = S - M - WW;
  }
}

__device__ __forceinline__ int row_low(unsigned long long x, unsigned long long y, int lane) {
  unsigned long long msk = __ballot((x | y) != 0ull);
  int hb = y ? (lane * 128 + 127 - __clzll(y)) : (lane * 128 + 63 - __clzll(x | 1ull));
  return msk ? __shfl(hb, 63 - __clzll(msk)) : -1;
}

// delta_1 reduction, lock-free with active lists + in-pass chain-through.
// state[r]: <2*pass = stable (untouched this pass); ==2*pass = in-flight
// (stamped, claim->writeback window); ==2*pass+1 = done (row readable).
// Invariant: listed rows own no pivots, so spiv[l] can be in-flight only
// during the short claim->writeback window -> bounded spin, no deadlock.
// Two interleaved chains per wave hide L2 row-read latency.
__global__ void __launch_bounds__(1024) k_reduce(const int* __restrict__ sd,
                                                 int nV, int nS,
                                                 float* __restrict__ out) {
  __shared__ int spiv[MAX_T];       // tri position -> owning edge row (or INF)
  __shared__ int lowA[MAX_E];
  __shared__ int state[MAX_E];
  __shared__ int lists[2][MAX_E];
  __shared__ int cnts[2];
  __shared__ int workIdx;
  __shared__ float ssum[16], smax[16];

  int tid = threadIdx.x;
  int lane = tid & 63;
  int wave = tid >> 6;
  int nE = ub_dim(sd, nS, 1) - nV;
  int nT = ub_dim(sd, nS, 2) - nV - nE;

  for (int i = tid; i < nT; i += 1024) spiv[i] = INF_I;
  for (int r = tid; r < nE; r += 1024) state[r] = -1;
  if (tid == 0) { cnts[0] = 0; cnts[1] = 0; }
  __syncthreads();

  // initial lows + claims (two rows in flight per wave to hide L2 latency)
  for (int r = wave; r < nE; r += 32) {
    int r2 = r + 16;
    bool h2 = (r2 < nE);
    int c1 = g_clr[r];
    int c2 = h2 ? g_clr[r2] : 1;
    unsigned long long ax = 0, ay = 0, bx = 0, by = 0;
    if (!c1 && lane < 36) {
      ulonglong2 v = *(const ulonglong2*)&g_rows[(size_t)r * TW + 2 * lane];
      ax = v.x; ay = v.y;
    }
    if (!c2 && lane < 36) {
      ulonglong2 v = *(const ulonglong2*)&g_rows[(size_t)r2 * TW + 2 * lane];
      bx = v.x; by = v.y;
    }
    int low1 = c1 ? -1 : row_low(ax, ay, lane);
    if (lane == 0) { lowA[r] = low1; if (low1 >= 0) atomicMin(&spiv[low1], r); }
    if (h2) {
      int low2 = c2 ? -1 : row_low(bx, by, lane);
      if (lane == 0) { lowA[r2] = low2; if (low2 >= 0) atomicMin(&spiv[low2], r2); }
    }
  }
  __syncthreads();
  for (int r = tid; r < nE; r += 1024) {
    int l = lowA[r];
    if (l >= 0 && spiv[l] != r) { int q = atomicAdd(&cnts[0], 1); lists[0][q] = r; }
  }
  __syncthreads();

  int pass = 0;
  int cnt = cnts[0];
  while (cnt > 0 && pass < 20000) {
    int cur = pass & 1, nxt = cur ^ 1;
    if (tid == 0) { cnts[nxt] = 0; workIdx = 0; }
    for (int i = tid; i < cnt; i += 1024) state[lists[cur][i]] = 2 * pass;
    __syncthreads();

    auto grab = [&](int& r, int& l, unsigned long long& wx, unsigned long long& wy, bool& md) {
      int idx = 0;
      if (lane == 0) idx = atomicAdd(&workIdx, 1);
      idx = __shfl(idx, 0);
      if (idx < cnt) {
        r = lists[cur][idx];
        l = lowA[r];
        md = false;
        wx = 0; wy = 0;
        if (lane < 36) {
          ulonglong2 v = *(const ulonglong2*)&g_rows[(size_t)r * TW + 2 * lane];
          wx = v.x; wy = v.y;
        }
      } else r = -1;
    };

    auto resolve = [&](int& r, int& l, unsigned long long& wx, unsigned long long& wy, bool& md,
                       int p, int st, unsigned long long px, unsigned long long py) {
      if (st >= 2 * pass) {
        if (st == 2 * pass) {                // in-flight: bounded spin
          int t = 0;
          while ((st = state[p]) == 2 * pass && ++t < 256) {}
        }
        if (st == 2 * pass) {                // timeout -> requeue self
          if (md && lane < 36) {
            ulonglong2 v; v.x = wx; v.y = wy;
            *(ulonglong2*)&g_rows[(size_t)r * TW + 2 * lane] = v;
          }
          if (lane == 0) { int q = atomicAdd(&cnts[nxt], 1); lists[nxt][q] = r; }
          grab(r, l, wx, wy, md);
          return;
        }
        __threadfence_block();               // acquire: re-read after done observed
        px = 0; py = 0;
        if (lane < 36) {
          ulonglong2 v = *(const ulonglong2*)&g_rows[(size_t)p * TW + 2 * lane];
          px = v.x; py = v.y;
        }
      }
      wx ^= px; wy ^= py; md = true;
      l = row_low(wx, wy, lane);
      if (lane == 0) lowA[r] = l;
      if (l < 0) {                           // zero row (theory: unreachable)
        grab(r, l, wx, wy, md);
        return;
      }
      int old = 0;
      if (lane == 0) old = atomicMin(&spiv[l], r);
      old = __shfl(old, 0);
      if (old > r) {                         // claim success: publish row, mark done
        if (lane < 36) {
          ulonglong2 v; v.x = wx; v.y = wy;
          *(ulonglong2*)&g_rows[(size_t)r * TW + 2 * lane] = v;
        }
        __threadfence_block();               // release: row visible before done
        if (lane == 0) {
          state[r] = 2 * pass + 1;
          if (old != INF_I) { int q = atomicAdd(&cnts[nxt], 1); lists[nxt][q] = old; }
        }
        grab(r, l, wx, wy, md);
      }
      // else: lost claim; slot stays active and keeps chaining
    };

    int rA = -1, lA = 0; unsigned long long wxA = 0, wyA = 0; bool mdA = false;
    int rB = -1, lB = 0; unsigned long long wxB = 0, wyB = 0; bool mdB = false;
    grab(rA, lA, wxA, wyA, mdA);
    grab(rB, lB, wxB, wyB, mdB);
    while (rA >= 0 || rB >= 0) {
      int pA = 0, stA = -1; unsigned long long pxA = 0, pyA = 0;
      int pB = 0, stB = -1; unsigned long long pxB = 0, pyB = 0;
      if (rA >= 0) {
        pA = spiv[lA];
        if (lane < 36) {
          ulonglong2 v = *(const ulonglong2*)&g_rows[(size_t)pA * TW + 2 * lane];
          pxA = v.x; pyA = v.y;
        }
        stA = state[pA];
      }
      if (rB >= 0) {
        pB = spiv[lB];
        if (lane < 36) {
          ulonglong2 v = *(const ulonglong2*)&g_rows[(size_t)pB * TW + 2 * lane];
          pxB = v.x; pyB = v.y;
        }
        stB = state[pB];
      }
      if (rA >= 0) resolve(rA, lA, wxA, wyA, mdA, pA, stA, pxA, pyA);
      if (rB >= 0) resolve(rB, lB, wxB, wyB, mdB, pB, stB, pxB, pyB);
    }
    __syncthreads();
    cnt = cnts[nxt];
    pass++;
  }

  // epilogue: pair (edge rank nE-1-r, tri rank nT-1-l); loss1 = sum - max
  float sum = 0.f, mx = 0.f;
  for (int l = tid; l < nT; l += 1024) {
    int r = spiv[l];
    if (r != INF_I) {
      float len = g_ef[nE - 1 - r] - g_tf[nT - 1 - l];
      sum += len;
      mx = fmaxf(mx, len);
    }
  }
  #pragma unroll
  for (int off = 32; off; off >>= 1) {
    sum += __shfl_xor(sum, off, 64);
    mx = fmaxf(mx, __shfl_xor(mx, off, 64));
  }
  if (lane == 0) { ssum[wave] = sum; smax[wave] = mx; }
  __syncthreads();
  if (tid == 0) {
    float S = 0.f, M = 0.f;
    for (int i = 0; i < 16; ++i) { S += ssum[i]; M = fmaxf(M, smax[i]); }
    out[0] = g_loss0 + S - M;
  }
}

extern "C" void kernel_launch(void* const* d_in, const int* in_sizes, int n_in,
                              void* d_out, int out_size, void* d_ws, size_t ws_size,
                              hipStream_t stream) {
  const float* beta = (const float*)d_in[0];
  const int*   sv   = (const int*)d_in[1];
  const int*   sd   = (const int*)d_in[2];
  const int*   bf   = (const int*)d_in[4];
  float* out = (float*)d_out;

  int nV = in_sizes[0];
  int nS = in_sizes[2];

  k_rankprep<<<RB_E + RB_T + RB_C, 256, 0, stream>>>(beta, sv, sd, nV, nS);
  k_ufsc<<<1 + TBLK, 256, 0, stream>>>(beta, sv, bf, sd, nV, nS);
  k_reduce<<<1, 1024, 0, stream>>>(sd, nV, nS, out);
}

// Round 7
// 275.701 us; speedup vs baseline: 1.1010x; 1.1010x over previous
//
#include <hip/hip_runtime.h>
#include <stdint.h>

// Fixed 8x8x8 grid complex: nV=512, nE=2863, nT=4410, nTet=2058, nS=9843.
// Dim-1 pairs via COHOMOLOGY (coboundary delta_1) + clearing of MST edges:
// rows = edges (reverse filtration order), bits = triangles (reverse order).
// Negative (MST) edges' rows would reduce to zero -> cleared upfront.
#define MAX_E 3072
#define MAX_T 4608
#define MAX_V 1024
#define TW    72     // u64 words per row >= ceil(nT/64); 2 words/lane, lanes 0..35
#define INF_I 0x7fffffff
#define RB_E  12     // edge-rank blocks
#define RB_T  18     // tri-rank blocks
#define RB_C  24     // clear blocks
#define TBLK  18     // scatter blocks = ceil(MAX_T/256)

typedef unsigned long long ull;

__device__ int   g_erank[MAX_E];             // edge local idx -> rank (f desc, idx asc)
__device__ int   g_eorder[MAX_E];            // rank -> edge local idx
__device__ float g_ef[MAX_E];                // f by edge rank
__device__ int   g_trank[MAX_T];             // tri local idx -> rank
__device__ float g_tf[MAX_T];                // f by tri rank
__device__ __attribute__((aligned(16))) ull g_rows[(size_t)MAX_E * TW];
__device__ int   g_mst[MAX_E];               // edge idx -> 1 if MST (negative) edge
__device__ int   g_clr[MAX_E];               // row rr -> 1 if cleared
__device__ float g_loss0;

// sd is sorted (verts, edges, tris, tets): first index with dim > d.
__device__ __forceinline__ int ub_dim(const int* __restrict__ sd, int nS, int d) {
  int lo = 0, hi = nS;
  while (lo < hi) { int mid = (lo + hi) >> 1; if (sd[mid] <= d) lo = mid + 1; else hi = mid; }
  return lo;
}

// K1: independent roles — edge ranks | tri ranks | UF (Boruvka) | row clear.
// UF is rank-independent (writes g_mst by edge idx), so all roles overlap.
union SharedK1 {
  struct { float sf[MAX_T]; } rank;
  struct {
    int par[MAX_V]; ull cand[MAX_V]; int hookTo[MAX_V];
    int eu[MAX_E], ev2[MAX_E];
    float efv[MAX_E];
    unsigned int ekey[MAX_E];
    unsigned short alive[2][MAX_E];
    unsigned char mstf[MAX_E];
  } uf;
};

__global__ void __launch_bounds__(256) k_main1(const float* __restrict__ beta,
                                               const int* __restrict__ sv,
                                               const int* __restrict__ sd,
                                               int nV, int nS) {
  __shared__ SharedK1 sh;
  __shared__ float aS[4], aM[4], aW[4];
  __shared__ int nNext, nRoots;
  int b = blockIdx.x, tid = threadIdx.x;
  int nE = ub_dim(sd, nS, 1) - nV;

  if (b < RB_E) {
    // ---- edge ranks (f desc, idx asc) by counting; f staged in LDS ----
    for (int j = tid; j < nE; j += 256) {
      const int* p = &sv[(size_t)(nV + j) * 4];
      sh.rank.sf[j] = fminf(beta[p[0]], beta[p[1]]);
    }
    __syncthreads();
    int i = b * 256 + tid;
    if (i >= nE) return;
    float fi = sh.rank.sf[i];
    int r = 0;
    for (int j = 0; j < nE; ++j) {
      float fj = sh.rank.sf[j];
      r += (fj > fi) || (fj == fi && j < i);
    }
    g_erank[i] = r;
    g_eorder[r] = i;
    g_ef[r] = fi;
    return;
  }
  if (b < RB_E + RB_T) {
    // ---- tri ranks ----
    int nT = ub_dim(sd, nS, 2) - nV - nE;
    int base = nV + nE;
    for (int j = tid; j < nT; j += 256) {
      const int* p = &sv[(size_t)(base + j) * 4];
      sh.rank.sf[j] = fminf(fminf(beta[p[0]], beta[p[1]]), beta[p[2]]);
    }
    __syncthreads();
    int i = (b - RB_E) * 256 + tid;
    if (i >= nT) return;
    float fi = sh.rank.sf[i];
    int r = 0;
    for (int j = 0; j < nT; ++j) {
      float fj = sh.rank.sf[j];
      r += (fj > fi) || (fj == fi && j < i);
    }
    g_trank[i] = r;
    g_tf[r] = fi;
    return;
  }
  if (b > RB_E + RB_T) {
    // ---- clear g_rows ----
    size_t i = (size_t)(b - RB_E - RB_T - 1) * 256 + tid;
    size_t stride = (size_t)RB_C * 256;
    for (size_t k = i; k < (size_t)MAX_E * TW; k += stride) g_rows[k] = 0ull;
    return;
  }

  // ---- UF role: loss0 = sum_v f(v) - max_v f(v) - W(canonical max ST).
  // Boruvka with STRICT keys (f desc, idx asc) == Kruskal's negative edge set.
  // Wave-aggregated compaction: one atomicAdd per wave, not per edge.
  int lane = tid & 63, wave = tid >> 6;
  for (int v = tid; v < nV; v += 256) sh.uf.par[v] = v;
  for (int e = tid; e < nE; e += 256) {
    int u = sv[(size_t)(nV + e) * 4];
    int v = sv[(size_t)(nV + e) * 4 + 1];
    sh.uf.eu[e] = u; sh.uf.ev2[e] = v;
    float fe = fminf(beta[u], beta[v]);
    sh.uf.efv[e] = fe;
    unsigned int bb = __float_as_uint(fe);
    sh.uf.ekey[e] = (bb & 0x80000000u) ? ~bb : (bb | 0x80000000u);  // orderable
    sh.uf.alive[0][e] = (unsigned short)e;
    sh.uf.mstf[e] = 0;
  }
  float s = 0.f, m = -3.0e38f;
  for (int v = tid; v < nV; v += 256) { float fv = beta[v]; s += fv; m = fmaxf(m, fv); }
  float W = 0.f;
  int nAlive = nE, cur = 0;
  __syncthreads();
  for (int phase = 0; phase < 20 && nAlive > 0; ++phase) {
    for (int v = tid; v < nV; v += 256) sh.uf.cand[v] = 0ull;
    if (tid == 0) { nNext = 0; nRoots = 0; }
    __syncthreads();
    for (int i0 = 0; i0 < nAlive; i0 += 256) {
      int i = i0 + tid;
      int e = -1, ra = 0, rb = 0;
      bool cross = false;
      if (i < nAlive) {
        e = sh.uf.alive[cur][i];
        ra = sh.uf.eu[e];  while (sh.uf.par[ra] != ra) ra = sh.uf.par[ra];
        rb = sh.uf.ev2[e]; while (sh.uf.par[rb] != rb) rb = sh.uf.par[rb];
        cross = (ra != rb);
      }
      ull mb = __ballot(cross);
      int base = 0;
      if (lane == 0 && mb) base = atomicAdd(&nNext, __popcll(mb));
      base = __shfl(base, 0);
      if (cross) {
        int off = __popcll(mb & ((1ull << lane) - 1ull));
        sh.uf.alive[cur ^ 1][base + off] = (unsigned short)e;
        // key: larger f wins; tie -> SMALLER edge idx wins (canonical order)
        ull key = ((ull)sh.uf.ekey[e] << 32) | (ull)(0xffffffffu - (unsigned)e);
        atomicMax(&sh.uf.cand[ra], key);
        atomicMax(&sh.uf.cand[rb], key);
      }
    }
    __syncthreads();
    for (int v = tid; v < nV; v += 256) {
      int t = -1;
      ull cv = sh.uf.cand[v];
      if (sh.uf.par[v] == v && cv) {
        int e = (int)(0xffffffffu - (unsigned)(cv & 0xffffffffu));
        int ra = sh.uf.eu[e];  while (sh.uf.par[ra] != ra) ra = sh.uf.par[ra];
        int rb = sh.uf.ev2[e]; while (sh.uf.par[rb] != rb) rb = sh.uf.par[rb];
        int other = (ra == v) ? rb : ra;
        if (sh.uf.cand[other] != cv || v < other) t = other;  // break 2-cycles
      }
      sh.uf.hookTo[v] = t;
    }
    __syncthreads();
    for (int v = tid; v < nV; v += 256) {
      int t = sh.uf.hookTo[v];
      if (t >= 0) {
        sh.uf.par[v] = t;
        int e = (int)(0xffffffffu - (unsigned)(sh.uf.cand[v] & 0xffffffffu));
        W += sh.uf.efv[e];
        sh.uf.mstf[e] = 1;                   // negative edge
      }
    }
    __syncthreads();
    for (int it = 0; it < 5; ++it) {
      for (int v = tid; v < nV; v += 256) {
        int p = sh.uf.par[v]; int gp = sh.uf.par[p];
        if (p != gp) sh.uf.par[v] = gp;
      }
      __syncthreads();
    }
    // ballot-based root count (no atomic storm)
    int loc = 0;
    for (int v = tid; v < nV; v += 256) loc += (sh.uf.par[v] == v);
    #pragma unroll
    for (int off = 32; off; off >>= 1) loc += __shfl_xor(loc, off, 64);
    if (lane == 0) atomicAdd(&nRoots, loc);
    __syncthreads();
    if (nRoots <= 1) break;
    nAlive = nNext;
    cur ^= 1;
    __syncthreads();                          // nNext read-before-reset fence
  }
  __syncthreads();
  // write MST flags once
  for (int e = tid; e < nE; e += 256) g_mst[e] = sh.uf.mstf[e];
  #pragma unroll
  for (int off = 32; off; off >>= 1) {
    s += __shfl_xor(s, off, 64);
    m = fmaxf(m, __shfl_xor(m, off, 64));
    W += __shfl_xor(W, off, 64);
  }
  if (lane == 0) { aS[wave] = s; aM[wave] = m; aW[wave] = W; }
  __syncthreads();
  if (tid == 0) {
    float S = 0.f, M = -3.0e38f, WW = 0.f;
    for (int i = 0; i < 4; ++i) { S += aS[i]; M = fmaxf(M, aM[i]); WW += aW[i]; }
    g_loss0 = S - M - WW;
  }
}

// K2: blocks [0,TBLK) scatter coboundary rows; block TBLK translates MST
// flags into cleared-row flags (rank space). Disjoint outputs.
__global__ void __launch_bounds__(256) k_scat(const int* __restrict__ bf,
                                              const int* __restrict__ sd,
                                              int nV, int nS) {
  int nE = ub_dim(sd, nS, 1) - nV;
  int tid = threadIdx.x;
  if (blockIdx.x == TBLK) {
    for (int r = tid; r < nE; r += 256)
      g_clr[nE - 1 - r] = g_mst[g_eorder[r]];
    return;
  }
  int nT = ub_dim(sd, nS, 2) - nV - nE;
  int t = blockIdx.x * 256 + tid;
  if (t >= nT) return;
  int lpos = nT - 1 - g_trank[t];
  size_t base = (size_t)2 * nE + (size_t)3 * t;
  ull bit = 1ull << (lpos & 63);
  int word = lpos >> 6;
  for (int j = 0; j < 3; ++j) {
    int e = bf[base + j] - nV;
    int rr = nE - 1 - g_erank[e];
    atomicOr(&g_rows[(size_t)rr * TW + word], bit);
  }
}

__device__ __forceinline__ int row_low(ull x, ull y, int lane) {
  ull msk = __ballot((x | y) != 0ull);
  int hb = y ? (lane * 128 + 127 - __clzll(y)) : (lane * 128 + 63 - __clzll(x | 1ull));
  return msk ? __shfl(hb, 63 - __clzll(msk)) : -1;
}

// delta_1 reduction, lock-free with active lists (R5 structure, known-good).
// Cleared rows never claim and are never read. Every surviving row ends with
// a distinct pivot.
__global__ void __launch_bounds__(1024) k_reduce(const int* __restrict__ sd,
                                                 int nV, int nS,
                                                 float* __restrict__ out) {
  __shared__ int spiv[MAX_T];       // tri position -> owning edge row (or INF)
  __shared__ int lowA[MAX_E];
  __shared__ int stamp[MAX_E];
  __shared__ int lists[2][MAX_E];
  __shared__ int cnts[2];
  __shared__ int workIdx;
  __shared__ float ssum[16], smax[16];

  int tid = threadIdx.x;
  int lane = tid & 63;
  int wave = tid >> 6;
  int nE = ub_dim(sd, nS, 1) - nV;
  int nT = ub_dim(sd, nS, 2) - nV - nE;

  for (int i = tid; i < nT; i += 1024) spiv[i] = INF_I;
  for (int r = tid; r < nE; r += 1024) stamp[r] = -1;
  if (tid == 0) { cnts[0] = 0; cnts[1] = 0; }
  __syncthreads();

  // initial lows + claims (two rows in flight per wave to hide L2 latency)
  for (int r = wave; r < nE; r += 32) {
    int r2 = r + 16;
    bool h2 = (r2 < nE);
    int c1 = g_clr[r];
    int c2 = h2 ? g_clr[r2] : 1;
    ull ax = 0, ay = 0, bx = 0, by = 0;
    if (!c1 && lane < 36) {
      ulonglong2 v = *(const ulonglong2*)&g_rows[(size_t)r * TW + 2 * lane];
      ax = v.x; ay = v.y;
    }
    if (!c2 && lane < 36) {
      ulonglong2 v = *(const ulonglong2*)&g_rows[(size_t)r2 * TW + 2 * lane];
      bx = v.x; by = v.y;
    }
    int low1 = c1 ? -1 : row_low(ax, ay, lane);
    if (lane == 0) { lowA[r] = low1; if (low1 >= 0) atomicMin(&spiv[low1], r); }
    if (h2) {
      int low2 = c2 ? -1 : row_low(bx, by, lane);
      if (lane == 0) { lowA[r2] = low2; if (low2 >= 0) atomicMin(&spiv[low2], r2); }
    }
  }
  __syncthreads();
  for (int r = tid; r < nE; r += 1024) {
    int l = lowA[r];
    if (l >= 0 && spiv[l] != r) { int q = atomicAdd(&cnts[0], 1); lists[0][q] = r; }
  }
  __syncthreads();

  int pass = 0;
  int cnt = cnts[0];
  while (cnt > 0 && pass < 50000) {
    int cur = pass & 1, nxt = cur ^ 1;
    if (tid == 0) { cnts[nxt] = 0; workIdx = 0; }
    for (int i = tid; i < cnt; i += 1024) stamp[lists[cur][i]] = pass;
    __syncthreads();
    for (;;) {
      int idx = 0;
      if (lane == 0) idx = atomicAdd(&workIdx, 1);
      idx = __shfl(idx, 0);
      if (idx >= cnt) break;
      int r = lists[cur][idx];
      int l = lowA[r];                       // >= 0 for every listed row
      ull wx = 0, wy = 0;
      bool loaded = false, modified = false;
      for (;;) {
        int p = spiv[l];                     // p < r always
        // prefetch winner's row; discarded if stamped (torn reads never used)
        ull px = 0, py = 0;
        if (lane < 36) {
          ulonglong2 v = *(const ulonglong2*)&g_rows[(size_t)p * TW + 2 * lane];
          px = v.x; py = v.y;
        }
        if (stamp[p] == pass) {              // winner busy this pass -> retry next
          if (lane == 0) { int q = atomicAdd(&cnts[nxt], 1); lists[nxt][q] = r; }
          break;
        }
        if (!loaded) {
          if (lane < 36) {
            ulonglong2 v = *(const ulonglong2*)&g_rows[(size_t)r * TW + 2 * lane];
            wx = v.x; wy = v.y;
          }
          loaded = true;
        }
        wx ^= px; wy ^= py;
        modified = true;
        l = row_low(wx, wy, lane);
        if (lane == 0) lowA[r] = l;
        if (l < 0) break;                    // unreachable for uncleared rows
        int old = 0;
        if (lane == 0) old = atomicMin(&spiv[l], r);
        old = __shfl(old, 0);
        if (old > r) {                       // claimed; evictee reacts next pass
          if (old != INF_I && lane == 0) { int q = atomicAdd(&cnts[nxt], 1); lists[nxt][q] = old; }
          break;
        }
        // old < r: lost claim; keep chaining
      }
      if (modified && l >= 0 && lane < 36) {
        ulonglong2 v; v.x = wx; v.y = wy;
        *(ulonglong2*)&g_rows[(size_t)r * TW + 2 * lane] = v;
      }
    }
    __syncthreads();
    cnt = cnts[nxt];
    pass++;
  }

  // epilogue: pair (edge rank nE-1-r, tri rank nT-1-l); loss1 = sum - max
  float sum = 0.f, mx = 0.f;
  for (int l = tid; l < nT; l += 1024) {
    int r = spiv[l];
    if (r != INF_I) {
      float len = g_ef[nE - 1 - r] - g_tf[nT - 1 - l];
      sum += len;
      mx = fmaxf(mx, len);
    }
  }
  #pragma unroll
  for (int off = 32; off; off >>= 1) {
    sum += __shfl_xor(sum, off, 64);
    mx = fmaxf(mx, __shfl_xor(mx, off, 64));
  }
  if (lane == 0) { ssum[wave] = sum; smax[wave] = mx; }
  __syncthreads();
  if (tid == 0) {
    float S = 0.f, M = 0.f;
    for (int i = 0; i < 16; ++i) { S += ssum[i]; M = fmaxf(M, smax[i]); }
    out[0] = g_loss0 + S - M;
  }
}

extern "C" void kernel_launch(void* const* d_in, const int* in_sizes, int n_in,
                              void* d_out, int out_size, void* d_ws, size_t ws_size,
                              hipStream_t stream) {
  const float* beta = (const float*)d_in[0];
  const int*   sv   = (const int*)d_in[1];
  const int*   sd   = (const int*)d_in[2];
  const int*   bf   = (const int*)d_in[4];
  float* out = (float*)d_out;

  int nV = in_sizes[0];
  int nS = in_sizes[2];

  k_main1<<<RB_E + RB_T + 1 + RB_C, 256, 0, stream>>>(beta, sv, sd, nV, nS);
  k_scat<<<TBLK + 1, 256, 0, stream>>>(bf, sd, nV, nS);
  k_reduce<<<1, 1024, 0, stream>>>(sd, nV, nS, out);
}

// Round 8
// 215.781 us; speedup vs baseline: 1.4067x; 1.2777x over previous
//
#include <hip/hip_runtime.h>
#include <stdint.h>

// Fixed 8x8x8 grid complex: nV=512, nE=2863, nT=4410, nTet=2058, nS=9843.
// Dim-1 pairs via COHOMOLOGY (coboundary delta_1) + clearing of MST edges:
// rows = edges (reverse filtration order), bits = triangles (reverse order).
// Negative (MST) edges' rows would reduce to zero -> cleared upfront.
#define MAX_E 3072
#define MAX_T 4608
#define MAX_V 1024
#define TW    72     // u64 words per row >= ceil(nT/64); 2 words/lane, lanes 0..35
#define INF_I 0x7fffffff
#define RB_E  12     // edge-rank blocks
#define RB_T  18     // tri-rank blocks
#define RB_C  24     // clear blocks
#define TBLK  18     // scatter blocks = ceil(MAX_T/256)

typedef unsigned long long ull;

__device__ int   g_erank[MAX_E];             // edge local idx -> rank (f desc, idx asc)
__device__ int   g_eorder[MAX_E];            // rank -> edge local idx
__device__ float g_ef[MAX_E];                // f by edge rank
__device__ int   g_trank[MAX_T];             // tri local idx -> rank
__device__ float g_tf[MAX_T];                // f by tri rank
__device__ __attribute__((aligned(16))) ull g_rows[(size_t)MAX_E * TW];
__device__ int   g_mst[MAX_E];               // edge idx -> 1 if MST (negative) edge
__device__ int   g_clr[MAX_E];               // row rr -> 1 if cleared
__device__ int   g_ilow[MAX_E];              // row rr -> initial low (max bit), -1 if none
__device__ float g_loss0;

// sd is sorted (verts, edges, tris, tets): first index with dim > d.
__device__ __forceinline__ int ub_dim(const int* __restrict__ sd, int nS, int d) {
  int lo = 0, hi = nS;
  while (lo < hi) { int mid = (lo + hi) >> 1; if (sd[mid] <= d) lo = mid + 1; else hi = mid; }
  return lo;
}

// K1: independent roles — edge ranks | tri ranks | UF (Boruvka) | row clear.
// UF is rank-independent (writes g_mst by edge idx), so all roles overlap.
union SharedK1 {
  struct { float sf[MAX_T]; } rank;
  struct {
    int par[MAX_V]; ull cand[MAX_V]; int hookTo[MAX_V];
    int eu[MAX_E], ev2[MAX_E];
    float efv[MAX_E];
    unsigned int ekey[MAX_E];
    unsigned short alive[2][MAX_E];
    unsigned char mstf[MAX_E];
  } uf;
};

__global__ void __launch_bounds__(256) k_main1(const float* __restrict__ beta,
                                               const int* __restrict__ sv,
                                               const int* __restrict__ sd,
                                               int nV, int nS) {
  __shared__ SharedK1 sh;
  __shared__ float aS[4], aM[4], aW[4];
  __shared__ int nNext, nRoots;
  int b = blockIdx.x, tid = threadIdx.x;
  int nE = ub_dim(sd, nS, 1) - nV;

  if (b < RB_E) {
    // ---- edge ranks (f desc, idx asc) by counting; f staged in LDS ----
    for (int j = tid; j < nE; j += 256) {
      const int* p = &sv[(size_t)(nV + j) * 4];
      sh.rank.sf[j] = fminf(beta[p[0]], beta[p[1]]);
    }
    __syncthreads();
    int i = b * 256 + tid;
    if (i >= nE) return;
    float fi = sh.rank.sf[i];
    int r = 0;
    for (int j = 0; j < nE; ++j) {
      float fj = sh.rank.sf[j];
      r += (fj > fi) || (fj == fi && j < i);
    }
    g_erank[i] = r;
    g_eorder[r] = i;
    g_ef[r] = fi;
    return;
  }
  if (b < RB_E + RB_T) {
    // ---- tri ranks ----
    int nT = ub_dim(sd, nS, 2) - nV - nE;
    int base = nV + nE;
    for (int j = tid; j < nT; j += 256) {
      const int* p = &sv[(size_t)(base + j) * 4];
      sh.rank.sf[j] = fminf(fminf(beta[p[0]], beta[p[1]]), beta[p[2]]);
    }
    __syncthreads();
    int i = (b - RB_E) * 256 + tid;
    if (i >= nT) return;
    float fi = sh.rank.sf[i];
    int r = 0;
    for (int j = 0; j < nT; ++j) {
      float fj = sh.rank.sf[j];
      r += (fj > fi) || (fj == fi && j < i);
    }
    g_trank[i] = r;
    g_tf[r] = fi;
    return;
  }
  if (b > RB_E + RB_T) {
    // ---- clear g_rows + init g_ilow ----
    size_t i = (size_t)(b - RB_E - RB_T - 1) * 256 + tid;
    size_t stride = (size_t)RB_C * 256;
    for (size_t k = i; k < (size_t)MAX_E * TW; k += stride) g_rows[k] = 0ull;
    for (size_t k = i; k < MAX_E; k += stride) g_ilow[k] = -1;
    return;
  }

  // ---- UF role: loss0 = sum_v f(v) - max_v f(v) - W(canonical max ST).
  // Boruvka with STRICT keys (f desc, idx asc) == Kruskal's negative edge set.
  // Wave-aggregated compaction: one atomicAdd per wave, not per edge.
  int lane = tid & 63, wave = tid >> 6;
  for (int v = tid; v < nV; v += 256) sh.uf.par[v] = v;
  for (int e = tid; e < nE; e += 256) {
    int u = sv[(size_t)(nV + e) * 4];
    int v = sv[(size_t)(nV + e) * 4 + 1];
    sh.uf.eu[e] = u; sh.uf.ev2[e] = v;
    float fe = fminf(beta[u], beta[v]);
    sh.uf.efv[e] = fe;
    unsigned int bb = __float_as_uint(fe);
    sh.uf.ekey[e] = (bb & 0x80000000u) ? ~bb : (bb | 0x80000000u);  // orderable
    sh.uf.alive[0][e] = (unsigned short)e;
    sh.uf.mstf[e] = 0;
  }
  float s = 0.f, m = -3.0e38f;
  for (int v = tid; v < nV; v += 256) { float fv = beta[v]; s += fv; m = fmaxf(m, fv); }
  float W = 0.f;
  int nAlive = nE, cur = 0;
  __syncthreads();
  for (int phase = 0; phase < 20 && nAlive > 0; ++phase) {
    for (int v = tid; v < nV; v += 256) sh.uf.cand[v] = 0ull;
    if (tid == 0) { nNext = 0; nRoots = 0; }
    __syncthreads();
    for (int i0 = 0; i0 < nAlive; i0 += 256) {
      int i = i0 + tid;
      int e = -1, ra = 0, rb = 0;
      bool cross = false;
      if (i < nAlive) {
        e = sh.uf.alive[cur][i];
        ra = sh.uf.eu[e];  while (sh.uf.par[ra] != ra) ra = sh.uf.par[ra];
        rb = sh.uf.ev2[e]; while (sh.uf.par[rb] != rb) rb = sh.uf.par[rb];
        cross = (ra != rb);
      }
      ull mb = __ballot(cross);
      int base = 0;
      if (lane == 0 && mb) base = atomicAdd(&nNext, __popcll(mb));
      base = __shfl(base, 0);
      if (cross) {
        int off = __popcll(mb & ((1ull << lane) - 1ull));
        sh.uf.alive[cur ^ 1][base + off] = (unsigned short)e;
        // key: larger f wins; tie -> SMALLER edge idx wins (canonical order)
        ull key = ((ull)sh.uf.ekey[e] << 32) | (ull)(0xffffffffu - (unsigned)e);
        atomicMax(&sh.uf.cand[ra], key);
        atomicMax(&sh.uf.cand[rb], key);
      }
    }
    __syncthreads();
    for (int v = tid; v < nV; v += 256) {
      int t = -1;
      ull cv = sh.uf.cand[v];
      if (sh.uf.par[v] == v && cv) {
        int e = (int)(0xffffffffu - (unsigned)(cv & 0xffffffffu));
        int ra = sh.uf.eu[e];  while (sh.uf.par[ra] != ra) ra = sh.uf.par[ra];
        int rb = sh.uf.ev2[e]; while (sh.uf.par[rb] != rb) rb = sh.uf.par[rb];
        int other = (ra == v) ? rb : ra;
        if (sh.uf.cand[other] != cv || v < other) t = other;  // break 2-cycles
      }
      sh.uf.hookTo[v] = t;
    }
    __syncthreads();
    for (int v = tid; v < nV; v += 256) {
      int t = sh.uf.hookTo[v];
      if (t >= 0) {
        sh.uf.par[v] = t;
        int e = (int)(0xffffffffu - (unsigned)(sh.uf.cand[v] & 0xffffffffu));
        W += sh.uf.efv[e];
        sh.uf.mstf[e] = 1;                   // negative edge
      }
    }
    __syncthreads();
    for (int it = 0; it < 5; ++it) {
      for (int v = tid; v < nV; v += 256) {
        int p = sh.uf.par[v]; int gp = sh.uf.par[p];
        if (p != gp) sh.uf.par[v] = gp;
      }
      __syncthreads();
    }
    // ballot-based root count (no atomic storm)
    int loc = 0;
    for (int v = tid; v < nV; v += 256) loc += (sh.uf.par[v] == v);
    #pragma unroll
    for (int off = 32; off; off >>= 1) loc += __shfl_xor(loc, off, 64);
    if (lane == 0) atomicAdd(&nRoots, loc);
    __syncthreads();
    if (nRoots <= 1) break;
    nAlive = nNext;
    cur ^= 1;
    __syncthreads();                          // nNext read-before-reset fence
  }
  __syncthreads();
  // write MST flags once
  for (int e = tid; e < nE; e += 256) g_mst[e] = sh.uf.mstf[e];
  #pragma unroll
  for (int off = 32; off; off >>= 1) {
    s += __shfl_xor(s, off, 64);
    m = fmaxf(m, __shfl_xor(m, off, 64));
    W += __shfl_xor(W, off, 64);
  }
  if (lane == 0) { aS[wave] = s; aM[wave] = m; aW[wave] = W; }
  __syncthreads();
  if (tid == 0) {
    float S = 0.f, M = -3.0e38f, WW = 0.f;
    for (int i = 0; i < 4; ++i) { S += aS[i]; M = fmaxf(M, aM[i]); WW += aW[i]; }
    g_loss0 = S - M - WW;
  }
}

// K2: blocks [0,TBLK) scatter coboundary rows + accumulate each row's initial
// low via atomicMax; block TBLK translates MST flags into cleared-row flags.
__global__ void __launch_bounds__(256) k_scat(const int* __restrict__ bf,
                                              const int* __restrict__ sd,
                                              int nV, int nS) {
  int nE = ub_dim(sd, nS, 1) - nV;
  int tid = threadIdx.x;
  if (blockIdx.x == TBLK) {
    for (int r = tid; r < nE; r += 256)
      g_clr[nE - 1 - r] = g_mst[g_eorder[r]];
    return;
  }
  int nT = ub_dim(sd, nS, 2) - nV - nE;
  int t = blockIdx.x * 256 + tid;
  if (t >= nT) return;
  int lpos = nT - 1 - g_trank[t];
  size_t base = (size_t)2 * nE + (size_t)3 * t;
  ull bit = 1ull << (lpos & 63);
  int word = lpos >> 6;
  for (int j = 0; j < 3; ++j) {
    int e = bf[base + j] - nV;
    int rr = nE - 1 - g_erank[e];
    atomicOr(&g_rows[(size_t)rr * TW + word], bit);
    atomicMax(&g_ilow[rr], lpos);
  }
}

__device__ __forceinline__ int row_low(ull x, ull y, int lane) {
  ull msk = __ballot((x | y) != 0ull);
  int hb = y ? (lane * 128 + 127 - __clzll(y)) : (lane * 128 + 63 - __clzll(x | 1ull));
  return msk ? __shfl(hb, 63 - __clzll(msk)) : -1;
}

// delta_1 reduction, lock-free with active lists (R5 bulk structure) plus:
//  - initial lows from g_ilow (no init row sweep; rows load lazily on 1st XOR)
//  - serial tail: when cnt <= 8, wave 0 follows all remaining eviction
//    cascades in-wave (no barriers/stamps; single actor => race-free;
//    pending <= cnt since each pop pushes <= 1 evictee; low strictly
//    decreases per XOR => terminates).
__global__ void __launch_bounds__(1024) k_reduce(const int* __restrict__ sd,
                                                 int nV, int nS,
                                                 float* __restrict__ out) {
  __shared__ int spiv[MAX_T];       // tri position -> owning edge row (or INF)
  __shared__ int lowA[MAX_E];
  __shared__ int stamp[MAX_E];
  __shared__ int lists[2][MAX_E];
  __shared__ int tailq[64];
  __shared__ int cnts[2];
  __shared__ int workIdx;
  __shared__ float ssum[16], smax[16];

  int tid = threadIdx.x;
  int lane = tid & 63;
  int wave = tid >> 6;
  int nE = ub_dim(sd, nS, 1) - nV;
  int nT = ub_dim(sd, nS, 2) - nV - nE;

  for (int i = tid; i < nT; i += 1024) spiv[i] = INF_I;
  for (int r = tid; r < nE; r += 1024) stamp[r] = -1;
  if (tid == 0) { cnts[0] = 0; cnts[1] = 0; }
  __syncthreads();

  // initial lows from g_ilow (no row reads) + claims
  for (int r = tid; r < nE; r += 1024) {
    int l = g_clr[r] ? -1 : g_ilow[r];
    lowA[r] = l;
    if (l >= 0) atomicMin(&spiv[l], r);
  }
  __syncthreads();
  for (int r = tid; r < nE; r += 1024) {
    int l = lowA[r];
    if (l >= 0 && spiv[l] != r) { int q = atomicAdd(&cnts[0], 1); lists[0][q] = r; }
  }
  __syncthreads();

  int pass = 0;
  int cnt = cnts[0];
  while (cnt > 0 && pass < 50000) {
    int cur = pass & 1, nxt = cur ^ 1;

    if (cnt <= 8) {
      // ---- serial tail: wave 0 resolves all remaining cascades ----
      if (wave == 0) {
        for (int i = lane; i < cnt; i += 64) tailq[i] = lists[cur][i];
        int head = 0, tl = cnt;
        while (head < tl) {
          int r = tailq[head & 63]; head++;
          int l = lowA[r];                   // row's current low (== lost pivot)
          ull wx = 0, wy = 0;
          bool loaded = false;
          for (;;) {
            int p = spiv[l];                 // settled winner, p < r
            ull px = 0, py = 0;
            if (lane < 36) {
              ulonglong2 v = *(const ulonglong2*)&g_rows[(size_t)p * TW + 2 * lane];
              px = v.x; py = v.y;
            }
            if (!loaded) {
              if (lane < 36) {
                ulonglong2 v = *(const ulonglong2*)&g_rows[(size_t)r * TW + 2 * lane];
                wx = v.x; wy = v.y;
              }
              loaded = true;
            }
            wx ^= px; wy ^= py;
            l = row_low(wx, wy, lane);
            if (l < 0) break;                // unreachable for uncleared rows
            int old = 0;
            if (lane == 0) old = atomicMin(&spiv[l], r);
            old = __shfl(old, 0);
            if (old > r) {                   // claimed: publish row, queue evictee
              if (lane < 36) {
                ulonglong2 v; v.x = wx; v.y = wy;
                *(ulonglong2*)&g_rows[(size_t)r * TW + 2 * lane] = v;
              }
              if (lane == 0) lowA[r] = l;
              if (old != INF_I) { if (lane == 0) tailq[tl & 63] = old; tl++; }
              break;
            }
            // old < r: lost claim; keep chaining through new owner
          }
        }
      }
      __syncthreads();
      break;
    }

    if (tid == 0) { cnts[nxt] = 0; workIdx = 0; }
    for (int i = tid; i < cnt; i += 1024) stamp[lists[cur][i]] = pass;
    __syncthreads();
    for (;;) {
      int idx = 0;
      if (lane == 0) idx = atomicAdd(&workIdx, 1);
      idx = __shfl(idx, 0);
      if (idx >= cnt) break;
      int r = lists[cur][idx];
      int l = lowA[r];                       // >= 0 for every listed row
      ull wx = 0, wy = 0;
      bool loaded = false, modified = false;
      for (;;) {
        int p = spiv[l];                     // p < r always
        // prefetch winner's row; discarded if stamped (torn reads never used)
        ull px = 0, py = 0;
        if (lane < 36) {
          ulonglong2 v = *(const ulonglong2*)&g_rows[(size_t)p * TW + 2 * lane];
          px = v.x; py = v.y;
        }
        if (stamp[p] == pass) {              // winner busy this pass -> retry next
          if (lane == 0) { int q = atomicAdd(&cnts[nxt], 1); lists[nxt][q] = r; }
          break;
        }
        if (!loaded) {
          if (lane < 36) {
            ulonglong2 v = *(const ulonglong2*)&g_rows[(size_t)r * TW + 2 * lane];
            wx = v.x; wy = v.y;
          }
          loaded = true;
        }
        wx ^= px; wy ^= py;
        modified = true;
        l = row_low(wx, wy, lane);
        if (lane == 0) lowA[r] = l;
        if (l < 0) break;                    // unreachable for uncleared rows
        int old = 0;
        if (lane == 0) old = atomicMin(&spiv[l], r);
        old = __shfl(old, 0);
        if (old > r) {                       // claimed; evictee reacts next pass
          if (old != INF_I && lane == 0) { int q = atomicAdd(&cnts[nxt], 1); lists[nxt][q] = old; }
          break;
        }
        // old < r: lost claim; keep chaining
      }
      if (modified && l >= 0 && lane < 36) {
        ulonglong2 v; v.x = wx; v.y = wy;
        *(ulonglong2*)&g_rows[(size_t)r * TW + 2 * lane] = v;
      }
    }
    __syncthreads();
    cnt = cnts[nxt];
    pass++;
  }

  // epilogue: pair (edge rank nE-1-r, tri rank nT-1-l); loss1 = sum - max
  float sum = 0.f, mx = 0.f;
  for (int l = tid; l < nT; l += 1024) {
    int r = spiv[l];
    if (r != INF_I) {
      float len = g_ef[nE - 1 - r] - g_tf[nT - 1 - l];
      sum += len;
      mx = fmaxf(mx, len);
    }
  }
  #pragma unroll
  for (int off = 32; off; off >>= 1) {
    sum += __shfl_xor(sum, off, 64);
    mx = fmaxf(mx, __shfl_xor(mx, off, 64));
  }
  if (lane == 0) { ssum[wave] = sum; smax[wave] = mx; }
  __syncthreads();
  if (tid == 0) {
    float S = 0.f, M = 0.f;
    for (int i = 0; i < 16; ++i) { S += ssum[i]; M = fmaxf(M, smax[i]); }
    out[0] = g_loss0 + S - M;
  }
}

extern "C" void kernel_launch(void* const* d_in, const int* in_sizes, int n_in,
                              void* d_out, int out_size, void* d_ws, size_t ws_size,
                              hipStream_t stream) {
  const float* beta = (const float*)d_in[0];
  const int*   sv   = (const int*)d_in[1];
  const int*   sd   = (const int*)d_in[2];
  const int*   bf   = (const int*)d_in[4];
  float* out = (float*)d_out;

  int nV = in_sizes[0];
  int nS = in_sizes[2];

  k_main1<<<RB_E + RB_T + 1 + RB_C, 256, 0, stream>>>(beta, sv, sd, nV, nS);
  k_scat<<<TBLK + 1, 256, 0, stream>>>(bf, sd, nV, nS);
  k_reduce<<<1, 1024, 0, stream>>>(sd, nV, nS, out);
}

// Round 9
// 208.988 us; speedup vs baseline: 1.4525x; 1.0325x over previous
//
#include <hip/hip_runtime.h>
#include <stdint.h>

// Fixed 8x8x8 grid complex: nV=512, nE=2863, nT=4410, nTet=2058, nS=9843.
// Dim-1 pairs via COHOMOLOGY (coboundary delta_1) + clearing of MST edges:
// rows = edges (reverse filtration order), bits = triangles (reverse order).
// Negative (MST) edges' rows would reduce to zero -> cleared upfront.
#define MAX_E 3072
#define MAX_T 4608
#define MAX_V 1024
#define TW    72     // u64 words per row >= ceil(nT/64); 2 words/lane, lanes 0..35
#define INF_I 0x7fffffff
#define RB_E  12     // edge-rank blocks
#define RB_T  18     // tri-rank blocks
#define RB_C  24     // clear blocks
#define TBLK  18     // scatter blocks = ceil(MAX_T/256)

typedef unsigned long long ull;

__device__ int   g_erank[MAX_E];             // edge local idx -> rank (f desc, idx asc)
__device__ int   g_eorder[MAX_E];            // rank -> edge local idx
__device__ float g_ef[MAX_E];                // f by edge rank
__device__ int   g_trank[MAX_T];             // tri local idx -> rank
__device__ float g_tf[MAX_T];                // f by tri rank
__device__ __attribute__((aligned(16))) ull g_rows[(size_t)MAX_E * TW];
__device__ int   g_mst[MAX_E];               // edge idx -> 1 if MST (negative) edge
__device__ int   g_clr[MAX_E];               // row rr -> 1 if cleared
__device__ int   g_ilow[MAX_E];              // row rr -> initial low (max bit), -1 if none
__device__ float g_loss0;

// sd is sorted (verts, edges, tris, tets): first index with dim > d.
__device__ __forceinline__ int ub_dim(const int* __restrict__ sd, int nS, int d) {
  int lo = 0, hi = nS;
  while (lo < hi) { int mid = (lo + hi) >> 1; if (sd[mid] <= d) lo = mid + 1; else hi = mid; }
  return lo;
}

// Rank of element i among n values in LDS: r = #{j : fj > fi} + #{j<i : fj == fi}.
// float4 reads (LDS broadcast across lanes, ds_read_b128) + branch-free tie
// arithmetic -> uniform trip count, ~n/4 vector reads instead of n dependent
// scalar reads (the R8 kernel was latency-bound here: ~120cyc/element).
__device__ __forceinline__ int rank_count(const float* __restrict__ sf, int n, int i, float fi) {
  int r = 0, j = 0;
  for (; j + 4 <= n; j += 4) {
    float4 a = *(const float4*)(sf + j);
    r += (a.x > fi) + ((a.x == fi) & (j + 0 < i));
    r += (a.y > fi) + ((a.y == fi) & (j + 1 < i));
    r += (a.z > fi) + ((a.z == fi) & (j + 2 < i));
    r += (a.w > fi) + ((a.w == fi) & (j + 3 < i));
  }
  for (; j < n; ++j) {
    float fj = sf[j];
    r += (fj > fi) + ((fj == fi) & (j < i));
  }
  return r;
}

// K1: independent roles — edge ranks | tri ranks | UF (Boruvka) | row clear.
// UF is rank-independent (writes g_mst by edge idx), so all roles overlap.
union SharedK1 {
  struct { alignas(16) float sf[MAX_T]; } rank;
  struct {
    int par[MAX_V]; ull cand[MAX_V]; int hookTo[MAX_V];
    int eu[MAX_E], ev2[MAX_E];
    float efv[MAX_E];
    unsigned int ekey[MAX_E];
    unsigned short alive[2][MAX_E];
    unsigned char mstf[MAX_E];
  } uf;
};

__global__ void __launch_bounds__(256) k_main1(const float* __restrict__ beta,
                                               const int* __restrict__ sv,
                                               const int* __restrict__ sd,
                                               int nV, int nS) {
  __shared__ SharedK1 sh;
  __shared__ float aS[4], aM[4], aW[4];
  __shared__ int nNext, nRoots;
  int b = blockIdx.x, tid = threadIdx.x;
  int nE = ub_dim(sd, nS, 1) - nV;

  if (b < RB_E) {
    // ---- edge ranks (f desc, idx asc) by vectorized counting ----
    for (int j = tid; j < nE; j += 256) {
      const int* p = &sv[(size_t)(nV + j) * 4];
      sh.rank.sf[j] = fminf(beta[p[0]], beta[p[1]]);
    }
    __syncthreads();
    int i = b * 256 + tid;
    if (i >= nE) return;
    float fi = sh.rank.sf[i];
    int r = rank_count(sh.rank.sf, nE, i, fi);
    g_erank[i] = r;
    g_eorder[r] = i;
    g_ef[r] = fi;
    return;
  }
  if (b < RB_E + RB_T) {
    // ---- tri ranks ----
    int nT = ub_dim(sd, nS, 2) - nV - nE;
    int base = nV + nE;
    for (int j = tid; j < nT; j += 256) {
      const int* p = &sv[(size_t)(base + j) * 4];
      sh.rank.sf[j] = fminf(fminf(beta[p[0]], beta[p[1]]), beta[p[2]]);
    }
    __syncthreads();
    int i = (b - RB_E) * 256 + tid;
    if (i >= nT) return;
    float fi = sh.rank.sf[i];
    int r = rank_count(sh.rank.sf, nT, i, fi);
    g_trank[i] = r;
    g_tf[r] = fi;
    return;
  }
  if (b > RB_E + RB_T) {
    // ---- clear g_rows + init g_ilow ----
    size_t i = (size_t)(b - RB_E - RB_T - 1) * 256 + tid;
    size_t stride = (size_t)RB_C * 256;
    for (size_t k = i; k < (size_t)MAX_E * TW; k += stride) g_rows[k] = 0ull;
    for (size_t k = i; k < MAX_E; k += stride) g_ilow[k] = -1;
    return;
  }

  // ---- UF role: loss0 = sum_v f(v) - max_v f(v) - W(canonical max ST).
  // Boruvka with STRICT keys (f desc, idx asc) == Kruskal's negative edge set.
  // Wave-aggregated compaction: one atomicAdd per wave, not per edge.
  int lane = tid & 63, wave = tid >> 6;
  for (int v = tid; v < nV; v += 256) sh.uf.par[v] = v;
  for (int e = tid; e < nE; e += 256) {
    int u = sv[(size_t)(nV + e) * 4];
    int v = sv[(size_t)(nV + e) * 4 + 1];
    sh.uf.eu[e] = u; sh.uf.ev2[e] = v;
    float fe = fminf(beta[u], beta[v]);
    sh.uf.efv[e] = fe;
    unsigned int bb = __float_as_uint(fe);
    sh.uf.ekey[e] = (bb & 0x80000000u) ? ~bb : (bb | 0x80000000u);  // orderable
    sh.uf.alive[0][e] = (unsigned short)e;
    sh.uf.mstf[e] = 0;
  }
  float s = 0.f, m = -3.0e38f;
  for (int v = tid; v < nV; v += 256) { float fv = beta[v]; s += fv; m = fmaxf(m, fv); }
  float W = 0.f;
  int nAlive = nE, cur = 0;
  __syncthreads();
  for (int phase = 0; phase < 20 && nAlive > 0; ++phase) {
    for (int v = tid; v < nV; v += 256) sh.uf.cand[v] = 0ull;
    if (tid == 0) { nNext = 0; nRoots = 0; }
    __syncthreads();
    for (int i0 = 0; i0 < nAlive; i0 += 256) {
      int i = i0 + tid;
      int e = -1, ra = 0, rb = 0;
      bool cross = false;
      if (i < nAlive) {
        e = sh.uf.alive[cur][i];
        ra = sh.uf.eu[e];  while (sh.uf.par[ra] != ra) ra = sh.uf.par[ra];
        rb = sh.uf.ev2[e]; while (sh.uf.par[rb] != rb) rb = sh.uf.par[rb];
        cross = (ra != rb);
      }
      ull mb = __ballot(cross);
      int base = 0;
      if (lane == 0 && mb) base = atomicAdd(&nNext, __popcll(mb));
      base = __shfl(base, 0);
      if (cross) {
        int off = __popcll(mb & ((1ull << lane) - 1ull));
        sh.uf.alive[cur ^ 1][base + off] = (unsigned short)e;
        // key: larger f wins; tie -> SMALLER edge idx wins (canonical order)
        ull key = ((ull)sh.uf.ekey[e] << 32) | (ull)(0xffffffffu - (unsigned)e);
        atomicMax(&sh.uf.cand[ra], key);
        atomicMax(&sh.uf.cand[rb], key);
      }
    }
    __syncthreads();
    for (int v = tid; v < nV; v += 256) {
      int t = -1;
      ull cv = sh.uf.cand[v];
      if (sh.uf.par[v] == v && cv) {
        int e = (int)(0xffffffffu - (unsigned)(cv & 0xffffffffu));
        int ra = sh.uf.eu[e];  while (sh.uf.par[ra] != ra) ra = sh.uf.par[ra];
        int rb = sh.uf.ev2[e]; while (sh.uf.par[rb] != rb) rb = sh.uf.par[rb];
        int other = (ra == v) ? rb : ra;
        if (sh.uf.cand[other] != cv || v < other) t = other;  // break 2-cycles
      }
      sh.uf.hookTo[v] = t;
    }
    __syncthreads();
    for (int v = tid; v < nV; v += 256) {
      int t = sh.uf.hookTo[v];
      if (t >= 0) {
        sh.uf.par[v] = t;
        int e = (int)(0xffffffffu - (unsigned)(sh.uf.cand[v] & 0xffffffffu));
        W += sh.uf.efv[e];
        sh.uf.mstf[e] = 1;                   // negative edge
      }
    }
    __syncthreads();
    for (int it = 0; it < 5; ++it) {
      for (int v = tid; v < nV; v += 256) {
        int p = sh.uf.par[v]; int gp = sh.uf.par[p];
        if (p != gp) sh.uf.par[v] = gp;
      }
      __syncthreads();
    }
    // ballot-based root count (no atomic storm)
    int loc = 0;
    for (int v = tid; v < nV; v += 256) loc += (sh.uf.par[v] == v);
    #pragma unroll
    for (int off = 32; off; off >>= 1) loc += __shfl_xor(loc, off, 64);
    if (lane == 0) atomicAdd(&nRoots, loc);
    __syncthreads();
    if (nRoots <= 1) break;
    nAlive = nNext;
    cur ^= 1;
    __syncthreads();                          // nNext read-before-reset fence
  }
  __syncthreads();
  // write MST flags once
  for (int e = tid; e < nE; e += 256) g_mst[e] = sh.uf.mstf[e];
  #pragma unroll
  for (int off = 32; off; off >>= 1) {
    s += __shfl_xor(s, off, 64);
    m = fmaxf(m, __shfl_xor(m, off, 64));
    W += __shfl_xor(W, off, 64);
  }
  if (lane == 0) { aS[wave] = s; aM[wave] = m; aW[wave] = W; }
  __syncthreads();
  if (tid == 0) {
    float S = 0.f, M = -3.0e38f, WW = 0.f;
    for (int i = 0; i < 4; ++i) { S += aS[i]; M = fmaxf(M, aM[i]); WW += aW[i]; }
    g_loss0 = S - M - WW;
  }
}

// K2: blocks [0,TBLK) scatter coboundary rows + accumulate each row's initial
// low via atomicMax; block TBLK translates MST flags into cleared-row flags.
__global__ void __launch_bounds__(256) k_scat(const int* __restrict__ bf,
                                              const int* __restrict__ sd,
                                              int nV, int nS) {
  int nE = ub_dim(sd, nS, 1) - nV;
  int tid = threadIdx.x;
  if (blockIdx.x == TBLK) {
    for (int r = tid; r < nE; r += 256)
      g_clr[nE - 1 - r] = g_mst[g_eorder[r]];
    return;
  }
  int nT = ub_dim(sd, nS, 2) - nV - nE;
  int t = blockIdx.x * 256 + tid;
  if (t >= nT) return;
  int lpos = nT - 1 - g_trank[t];
  size_t base = (size_t)2 * nE + (size_t)3 * t;
  ull bit = 1ull << (lpos & 63);
  int word = lpos >> 6;
  for (int j = 0; j < 3; ++j) {
    int e = bf[base + j] - nV;
    int rr = nE - 1 - g_erank[e];
    atomicOr(&g_rows[(size_t)rr * TW + word], bit);
    atomicMax(&g_ilow[rr], lpos);
  }
}

__device__ __forceinline__ int row_low(ull x, ull y, int lane) {
  ull msk = __ballot((x | y) != 0ull);
  int hb = y ? (lane * 128 + 127 - __clzll(y)) : (lane * 128 + 63 - __clzll(x | 1ull));
  return msk ? __shfl(hb, 63 - __clzll(msk)) : -1;
}

// delta_1 reduction, lock-free with active lists (R5 bulk structure) plus:
//  - initial lows from g_ilow (no init row sweep; rows load lazily on 1st XOR)
//  - serial tail: when cnt <= 8, wave 0 follows all remaining eviction
//    cascades in-wave (no barriers/stamps; single actor => race-free;
//    pending <= cnt since each pop pushes <= 1 evictee; low strictly
//    decreases per XOR => terminates).
__global__ void __launch_bounds__(1024) k_reduce(const int* __restrict__ sd,
                                                 int nV, int nS,
                                                 float* __restrict__ out) {
  __shared__ int spiv[MAX_T];       // tri position -> owning edge row (or INF)
  __shared__ int lowA[MAX_E];
  __shared__ int stamp[MAX_E];
  __shared__ int lists[2][MAX_E];
  __shared__ int tailq[64];
  __shared__ int cnts[2];
  __shared__ int workIdx;
  __shared__ float ssum[16], smax[16];

  int tid = threadIdx.x;
  int lane = tid & 63;
  int wave = tid >> 6;
  int nE = ub_dim(sd, nS, 1) - nV;
  int nT = ub_dim(sd, nS, 2) - nV - nE;

  for (int i = tid; i < nT; i += 1024) spiv[i] = INF_I;
  for (int r = tid; r < nE; r += 1024) stamp[r] = -1;
  if (tid == 0) { cnts[0] = 0; cnts[1] = 0; }
  __syncthreads();

  // initial lows from g_ilow (no row reads) + claims
  for (int r = tid; r < nE; r += 1024) {
    int l = g_clr[r] ? -1 : g_ilow[r];
    lowA[r] = l;
    if (l >= 0) atomicMin(&spiv[l], r);
  }
  __syncthreads();
  for (int r = tid; r < nE; r += 1024) {
    int l = lowA[r];
    if (l >= 0 && spiv[l] != r) { int q = atomicAdd(&cnts[0], 1); lists[0][q] = r; }
  }
  __syncthreads();

  int pass = 0;
  int cnt = cnts[0];
  while (cnt > 0 && pass < 50000) {
    int cur = pass & 1, nxt = cur ^ 1;

    if (cnt <= 8) {
      // ---- serial tail: wave 0 resolves all remaining cascades ----
      if (wave == 0) {
        for (int i = lane; i < cnt; i += 64) tailq[i] = lists[cur][i];
        int head = 0, tl = cnt;
        while (head < tl) {
          int r = tailq[head & 63]; head++;
          int l = lowA[r];                   // row's current low (== lost pivot)
          ull wx = 0, wy = 0;
          bool loaded = false;
          for (;;) {
            int p = spiv[l];                 // settled winner, p < r
            ull px = 0, py = 0;
            if (lane < 36) {
              ulonglong2 v = *(const ulonglong2*)&g_rows[(size_t)p * TW + 2 * lane];
              px = v.x; py = v.y;
            }
            if (!loaded) {
              if (lane < 36) {
                ulonglong2 v = *(const ulonglong2*)&g_rows[(size_t)r * TW + 2 * lane];
                wx = v.x; wy = v.y;
              }
              loaded = true;
            }
            wx ^= px; wy ^= py;
            l = row_low(wx, wy, lane);
            if (l < 0) break;                // unreachable for uncleared rows
            int old = 0;
            if (lane == 0) old = atomicMin(&spiv[l], r);
            old = __shfl(old, 0);
            if (old > r) {                   // claimed: publish row, queue evictee
              if (lane < 36) {
                ulonglong2 v; v.x = wx; v.y = wy;
                *(ulonglong2*)&g_rows[(size_t)r * TW + 2 * lane] = v;
              }
              if (lane == 0) lowA[r] = l;
              if (old != INF_I) { if (lane == 0) tailq[tl & 63] = old; tl++; }
              break;
            }
            // old < r: lost claim; keep chaining through new owner
          }
        }
      }
      __syncthreads();
      break;
    }

    if (tid == 0) { cnts[nxt] = 0; workIdx = 0; }
    for (int i = tid; i < cnt; i += 1024) stamp[lists[cur][i]] = pass;
    __syncthreads();
    for (;;) {
      int idx = 0;
      if (lane == 0) idx = atomicAdd(&workIdx, 1);
      idx = __shfl(idx, 0);
      if (idx >= cnt) break;
      int r = lists[cur][idx];
      int l = lowA[r];                       // >= 0 for every listed row
      ull wx = 0, wy = 0;
      bool loaded = false, modified = false;
      for (;;) {
        int p = spiv[l];                     // p < r always
        // prefetch winner's row; discarded if stamped (torn reads never used)
        ull px = 0, py = 0;
        if (lane < 36) {
          ulonglong2 v = *(const ulonglong2*)&g_rows[(size_t)p * TW + 2 * lane];
          px = v.x; py = v.y;
        }
        if (stamp[p] == pass) {              // winner busy this pass -> retry next
          if (lane == 0) { int q = atomicAdd(&cnts[nxt], 1); lists[nxt][q] = r; }
          break;
        }
        if (!loaded) {
          if (lane < 36) {
            ulonglong2 v = *(const ulonglong2*)&g_rows[(size_t)r * TW + 2 * lane];
            wx = v.x; wy = v.y;
          }
          loaded = true;
        }
        wx ^= px; wy ^= py;
        modified = true;
        l = row_low(wx, wy, lane);
        if (lane == 0) lowA[r] = l;
        if (l < 0) break;                    // unreachable for uncleared rows
        int old = 0;
        if (lane == 0) old = atomicMin(&spiv[l], r);
        old = __shfl(old, 0);
        if (old > r) {                       // claimed; evictee reacts next pass
          if (old != INF_I && lane == 0) { int q = atomicAdd(&cnts[nxt], 1); lists[nxt][q] = old; }
          break;
        }
        // old < r: lost claim; keep chaining
      }
      if (modified && l >= 0 && lane < 36) {
        ulonglong2 v; v.x = wx; v.y = wy;
        *(ulonglong2*)&g_rows[(size_t)r * TW + 2 * lane] = v;
      }
    }
    __syncthreads();
    cnt = cnts[nxt];
    pass++;
  }

  // epilogue: pair (edge rank nE-1-r, tri rank nT-1-l); loss1 = sum - max
  float sum = 0.f, mx = 0.f;
  for (int l = tid; l < nT; l += 1024) {
    int r = spiv[l];
    if (r != INF_I) {
      float len = g_ef[nE - 1 - r] - g_tf[nT - 1 - l];
      sum += len;
      mx = fmaxf(mx, len);
    }
  }
  #pragma unroll
  for (int off = 32; off; off >>= 1) {
    sum += __shfl_xor(sum, off, 64);
    mx = fmaxf(mx, __shfl_xor(mx, off, 64));
  }
  if (lane == 0) { ssum[wave] = sum; smax[wave] = mx; }
  __syncthreads();
  if (tid == 0) {
    float S = 0.f, M = 0.f;
    for (int i = 0; i < 16; ++i) { S += ssum[i]; M = fmaxf(M, smax[i]); }
    out[0] = g_loss0 + S - M;
  }
}

extern "C" void kernel_launch(void* const* d_in, const int* in_sizes, int n_in,
                              void* d_out, int out_size, void* d_ws, size_t ws_size,
                              hipStream_t stream) {
  const float* beta = (const float*)d_in[0];
  const int*   sv   = (const int*)d_in[1];
  const int*   sd   = (const int*)d_in[2];
  const int*   bf   = (const int*)d_in[4];
  float* out = (float*)d_out;

  int nV = in_sizes[0];
  int nS = in_sizes[2];

  k_main1<<<RB_E + RB_T + 1 + RB_C, 256, 0, stream>>>(beta, sv, sd, nV, nS);
  k_scat<<<TBLK + 1, 256, 0, stream>>>(bf, sd, nV, nS);
  k_reduce<<<1, 1024, 0, stream>>>(sd, nV, nS, out);
}

// Round 10
// 172.354 us; speedup vs baseline: 1.7612x; 1.2125x over previous
//
#include <hip/hip_runtime.h>
#include <stdint.h>

// Fixed 8x8x8 grid complex: nV=512, nE=2863, nT=4410, nTet=2058, nS=9843.
// Dim-1 pairs via COHOMOLOGY (coboundary delta_1) + clearing of MST edges:
// rows = edges (reverse filtration order), bits = triangles (reverse order).
// Negative (MST) edges' rows would reduce to zero -> cleared upfront.
#define MAX_E 3072
#define MAX_T 4608
#define MAX_V 1024
#define TW    72     // u64 words per row >= ceil(nT/64); 2 words/lane, lanes 0..35
#define INF_I 0x7fffffff
#define RB_E  12     // edge-rank blocks
#define RB_T  18     // tri-rank blocks
#define RB_C  24     // clear blocks
#define TBLK  18     // scatter blocks = ceil(MAX_T/256)

typedef unsigned long long ull;

__device__ int   g_erank[MAX_E];             // edge local idx -> rank (f desc, idx asc)
__device__ int   g_eorder[MAX_E];            // rank -> edge local idx
__device__ float g_ef[MAX_E];                // f by edge rank
__device__ int   g_trank[MAX_T];             // tri local idx -> rank
__device__ float g_tf[MAX_T];                // f by tri rank
__device__ __attribute__((aligned(16))) ull g_rows[(size_t)MAX_E * TW];
__device__ int   g_mst[MAX_E];               // edge idx -> 1 if MST (negative) edge
__device__ int   g_clr[MAX_E];               // row rr -> 1 if cleared
__device__ int   g_ilow[MAX_E];              // row rr -> initial low (max bit), -1 if none
__device__ float g_loss0;

// sd is sorted (verts, edges, tris, tets): first index with dim > d.
__device__ __forceinline__ int ub_dim(const int* __restrict__ sd, int nS, int d) {
  int lo = 0, hi = nS;
  while (lo < hi) { int mid = (lo + hi) >> 1; if (sd[mid] <= d) lo = mid + 1; else hi = mid; }
  return lo;
}

// Orderable key: key_j > key_i  <=>  (fj > fi) || (fj == fi && j < i).
__device__ __forceinline__ ull rank_key(float f, int j) {
  unsigned bb = __float_as_uint(f);
  unsigned ord = (bb & 0x80000000u) ? ~bb : (bb | 0x80000000u);
  return ((ull)ord << 32) | (ull)(0xffffffffu - (unsigned)j);
}

// Count keys > ki with 4 independent ds_read_b128 in flight per iteration
// (ILP hides LDS latency: rank blocks run 1 wave/SIMD, no TLP available).
__device__ __forceinline__ int rank_count64(const ull* __restrict__ sk, int n, ull ki) {
  int r = 0, j = 0;
  for (; j + 8 <= n; j += 8) {
    ulonglong2 a = *(const ulonglong2*)(sk + j);
    ulonglong2 b = *(const ulonglong2*)(sk + j + 2);
    ulonglong2 c = *(const ulonglong2*)(sk + j + 4);
    ulonglong2 d = *(const ulonglong2*)(sk + j + 6);
    r += (int)(a.x > ki) + (int)(a.y > ki) + (int)(b.x > ki) + (int)(b.y > ki)
       + (int)(c.x > ki) + (int)(c.y > ki) + (int)(d.x > ki) + (int)(d.y > ki);
  }
  for (; j < n; ++j) r += (int)(sk[j] > ki);
  return r;
}

// K1: independent roles — edge ranks | tri ranks | UF (Boruvka) | row clear.
// UF is rank-independent (writes g_mst by edge idx), so all roles overlap.
union SharedK1 {
  struct { alignas(16) ull sk[MAX_T]; } rank;
  struct {
    int par[MAX_V]; ull cand[MAX_V]; int hookTo[MAX_V];
    int eu[MAX_E], ev2[MAX_E];
    float efv[MAX_E];
    unsigned int ekey[MAX_E];
    unsigned short alive[2][MAX_E];
    unsigned char mstf[MAX_E];
  } uf;
};

__global__ void __launch_bounds__(256) k_main1(const float* __restrict__ beta,
                                               const int* __restrict__ sv,
                                               const int* __restrict__ sd,
                                               int nV, int nS) {
  __shared__ SharedK1 sh;
  __shared__ float aS[4], aM[4], aW[4];
  __shared__ int nNext, nRoots;
  int b = blockIdx.x, tid = threadIdx.x;
  int nE = ub_dim(sd, nS, 1) - nV;

  if (b < RB_E) {
    // ---- edge ranks via u64-key counting ----
    int i = b * 256 + tid;
    float fi = 0.f;
    for (int j = tid; j < nE; j += 256) {     // j==i hit here (j ≡ tid mod 256)
      const int* p = &sv[(size_t)(nV + j) * 4];
      float fj = fminf(beta[p[0]], beta[p[1]]);
      if (j == i) fi = fj;
      sh.rank.sk[j] = rank_key(fj, j);
    }
    __syncthreads();
    if (i >= nE) return;
    int r = rank_count64(sh.rank.sk, nE, sh.rank.sk[i]);
    g_erank[i] = r;
    g_eorder[r] = i;
    g_ef[r] = fi;
    return;
  }
  if (b < RB_E + RB_T) {
    // ---- tri ranks ----
    int nT = ub_dim(sd, nS, 2) - nV - nE;
    int base = nV + nE;
    int i = (b - RB_E) * 256 + tid;
    float fi = 0.f;
    for (int j = tid; j < nT; j += 256) {
      const int* p = &sv[(size_t)(base + j) * 4];
      float fj = fminf(fminf(beta[p[0]], beta[p[1]]), beta[p[2]]);
      if (j == i) fi = fj;
      sh.rank.sk[j] = rank_key(fj, j);
    }
    __syncthreads();
    if (i >= nT) return;
    int r = rank_count64(sh.rank.sk, nT, sh.rank.sk[i]);
    g_trank[i] = r;
    g_tf[r] = fi;
    return;
  }
  if (b > RB_E + RB_T) {
    // ---- clear g_rows + init g_ilow ----
    size_t i = (size_t)(b - RB_E - RB_T - 1) * 256 + tid;
    size_t stride = (size_t)RB_C * 256;
    for (size_t k = i; k < (size_t)MAX_E * TW; k += stride) g_rows[k] = 0ull;
    for (size_t k = i; k < MAX_E; k += stride) g_ilow[k] = -1;
    return;
  }

  // ---- UF role: loss0 = sum_v f(v) - max_v f(v) - W(canonical max ST).
  // Boruvka with STRICT keys (f desc, idx asc) == Kruskal's negative edge set.
  // Wave-aggregated compaction: one atomicAdd per wave, not per edge.
  int lane = tid & 63, wave = tid >> 6;
  for (int v = tid; v < nV; v += 256) sh.uf.par[v] = v;
  for (int e = tid; e < nE; e += 256) {
    int u = sv[(size_t)(nV + e) * 4];
    int v = sv[(size_t)(nV + e) * 4 + 1];
    sh.uf.eu[e] = u; sh.uf.ev2[e] = v;
    float fe = fminf(beta[u], beta[v]);
    sh.uf.efv[e] = fe;
    unsigned int bb = __float_as_uint(fe);
    sh.uf.ekey[e] = (bb & 0x80000000u) ? ~bb : (bb | 0x80000000u);  // orderable
    sh.uf.alive[0][e] = (unsigned short)e;
    sh.uf.mstf[e] = 0;
  }
  float s = 0.f, m = -3.0e38f;
  for (int v = tid; v < nV; v += 256) { float fv = beta[v]; s += fv; m = fmaxf(m, fv); }
  float W = 0.f;
  int nAlive = nE, cur = 0;
  __syncthreads();
  for (int phase = 0; phase < 20 && nAlive > 0; ++phase) {
    for (int v = tid; v < nV; v += 256) sh.uf.cand[v] = 0ull;
    if (tid == 0) { nNext = 0; nRoots = 0; }
    __syncthreads();
    for (int i0 = 0; i0 < nAlive; i0 += 256) {
      int i = i0 + tid;
      int e = -1, ra = 0, rb = 0;
      bool cross = false;
      if (i < nAlive) {
        e = sh.uf.alive[cur][i];
        ra = sh.uf.eu[e];  while (sh.uf.par[ra] != ra) ra = sh.uf.par[ra];
        rb = sh.uf.ev2[e]; while (sh.uf.par[rb] != rb) rb = sh.uf.par[rb];
        cross = (ra != rb);
      }
      ull mb = __ballot(cross);
      int base = 0;
      if (lane == 0 && mb) base = atomicAdd(&nNext, __popcll(mb));
      base = __shfl(base, 0);
      if (cross) {
        int off = __popcll(mb & ((1ull << lane) - 1ull));
        sh.uf.alive[cur ^ 1][base + off] = (unsigned short)e;
        // key: larger f wins; tie -> SMALLER edge idx wins (canonical order)
        ull key = ((ull)sh.uf.ekey[e] << 32) | (ull)(0xffffffffu - (unsigned)e);
        atomicMax(&sh.uf.cand[ra], key);
        atomicMax(&sh.uf.cand[rb], key);
      }
    }
    __syncthreads();
    for (int v = tid; v < nV; v += 256) {
      int t = -1;
      ull cv = sh.uf.cand[v];
      if (sh.uf.par[v] == v && cv) {
        int e = (int)(0xffffffffu - (unsigned)(cv & 0xffffffffu));
        int ra = sh.uf.eu[e];  while (sh.uf.par[ra] != ra) ra = sh.uf.par[ra];
        int rb = sh.uf.ev2[e]; while (sh.uf.par[rb] != rb) rb = sh.uf.par[rb];
        int other = (ra == v) ? rb : ra;
        if (sh.uf.cand[other] != cv || v < other) t = other;  // break 2-cycles
      }
      sh.uf.hookTo[v] = t;
    }
    __syncthreads();
    for (int v = tid; v < nV; v += 256) {
      int t = sh.uf.hookTo[v];
      if (t >= 0) {
        sh.uf.par[v] = t;
        int e = (int)(0xffffffffu - (unsigned)(sh.uf.cand[v] & 0xffffffffu));
        W += sh.uf.efv[e];
        sh.uf.mstf[e] = 1;                   // negative edge
      }
    }
    __syncthreads();
    for (int it = 0; it < 5; ++it) {
      for (int v = tid; v < nV; v += 256) {
        int p = sh.uf.par[v]; int gp = sh.uf.par[p];
        if (p != gp) sh.uf.par[v] = gp;
      }
      __syncthreads();
    }
    // ballot-based root count (no atomic storm)
    int loc = 0;
    for (int v = tid; v < nV; v += 256) loc += (sh.uf.par[v] == v);
    #pragma unroll
    for (int off = 32; off; off >>= 1) loc += __shfl_xor(loc, off, 64);
    if (lane == 0) atomicAdd(&nRoots, loc);
    __syncthreads();
    if (nRoots <= 1) break;
    nAlive = nNext;
    cur ^= 1;
    __syncthreads();                          // nNext read-before-reset fence
  }
  __syncthreads();
  // write MST flags once
  for (int e = tid; e < nE; e += 256) g_mst[e] = sh.uf.mstf[e];
  #pragma unroll
  for (int off = 32; off; off >>= 1) {
    s += __shfl_xor(s, off, 64);
    m = fmaxf(m, __shfl_xor(m, off, 64));
    W += __shfl_xor(W, off, 64);
  }
  if (lane == 0) { aS[wave] = s; aM[wave] = m; aW[wave] = W; }
  __syncthreads();
  if (tid == 0) {
    float S = 0.f, M = -3.0e38f, WW = 0.f;
    for (int i = 0; i < 4; ++i) { S += aS[i]; M = fmaxf(M, aM[i]); WW += aW[i]; }
    g_loss0 = S - M - WW;
  }
}

// K2: blocks [0,TBLK) scatter coboundary rows + accumulate each row's initial
// low via atomicMax; block TBLK translates MST flags into cleared-row flags.
__global__ void __launch_bounds__(256) k_scat(const int* __restrict__ bf,
                                              const int* __restrict__ sd,
                                              int nV, int nS) {
  int nE = ub_dim(sd, nS, 1) - nV;
  int tid = threadIdx.x;
  if (blockIdx.x == TBLK) {
    for (int r = tid; r < nE; r += 256)
      g_clr[nE - 1 - r] = g_mst[g_eorder[r]];
    return;
  }
  int nT = ub_dim(sd, nS, 2) - nV - nE;
  int t = blockIdx.x * 256 + tid;
  if (t >= nT) return;
  int lpos = nT - 1 - g_trank[t];
  size_t base = (size_t)2 * nE + (size_t)3 * t;
  ull bit = 1ull << (lpos & 63);
  int word = lpos >> 6;
  for (int j = 0; j < 3; ++j) {
    int e = bf[base + j] - nV;
    int rr = nE - 1 - g_erank[e];
    atomicOr(&g_rows[(size_t)rr * TW + word], bit);
    atomicMax(&g_ilow[rr], lpos);
  }
}

__device__ __forceinline__ int row_low(ull x, ull y, int lane) {
  ull msk = __ballot((x | y) != 0ull);
  int hb = y ? (lane * 128 + 127 - __clzll(y)) : (lane * 128 + 63 - __clzll(x | 1ull));
  return msk ? __shfl(hb, 63 - __clzll(msk)) : -1;
}

// delta_1 reduction, lock-free with active lists (R5 bulk structure) plus:
//  - initial lows from g_ilow (no init row sweep; rows load lazily on 1st XOR)
//  - serial tail: when cnt <= 8, wave 0 follows all remaining eviction
//    cascades in-wave (no barriers/stamps; single actor => race-free;
//    pending <= cnt since each pop pushes <= 1 evictee; low strictly
//    decreases per XOR => terminates).
__global__ void __launch_bounds__(1024) k_reduce(const int* __restrict__ sd,
                                                 int nV, int nS,
                                                 float* __restrict__ out) {
  __shared__ int spiv[MAX_T];       // tri position -> owning edge row (or INF)
  __shared__ int lowA[MAX_E];
  __shared__ int stamp[MAX_E];
  __shared__ int lists[2][MAX_E];
  __shared__ int tailq[64];
  __shared__ int cnts[2];
  __shared__ int workIdx;
  __shared__ float ssum[16], smax[16];

  int tid = threadIdx.x;
  int lane = tid & 63;
  int wave = tid >> 6;
  int nE = ub_dim(sd, nS, 1) - nV;
  int nT = ub_dim(sd, nS, 2) - nV - nE;

  for (int i = tid; i < nT; i += 1024) spiv[i] = INF_I;
  for (int r = tid; r < nE; r += 1024) stamp[r] = -1;
  if (tid == 0) { cnts[0] = 0; cnts[1] = 0; }
  __syncthreads();

  // initial lows from g_ilow (no row reads) + claims
  for (int r = tid; r < nE; r += 1024) {
    int l = g_clr[r] ? -1 : g_ilow[r];
    lowA[r] = l;
    if (l >= 0) atomicMin(&spiv[l], r);
  }
  __syncthreads();
  for (int r = tid; r < nE; r += 1024) {
    int l = lowA[r];
    if (l >= 0 && spiv[l] != r) { int q = atomicAdd(&cnts[0], 1); lists[0][q] = r; }
  }
  __syncthreads();

  int pass = 0;
  int cnt = cnts[0];
  while (cnt > 0 && pass < 50000) {
    int cur = pass & 1, nxt = cur ^ 1;

    if (cnt <= 8) {
      // ---- serial tail: wave 0 resolves all remaining cascades ----
      if (wave == 0) {
        for (int i = lane; i < cnt; i += 64) tailq[i] = lists[cur][i];
        int head = 0, tl = cnt;
        while (head < tl) {
          int r = tailq[head & 63]; head++;
          int l = lowA[r];                   // row's current low (== lost pivot)
          ull wx = 0, wy = 0;
          bool loaded = false;
          for (;;) {
            int p = spiv[l];                 // settled winner, p < r
            ull px = 0, py = 0;
            if (lane < 36) {
              ulonglong2 v = *(const ulonglong2*)&g_rows[(size_t)p * TW + 2 * lane];
              px = v.x; py = v.y;
            }
            if (!loaded) {
              if (lane < 36) {
                ulonglong2 v = *(const ulonglong2*)&g_rows[(size_t)r * TW + 2 * lane];
                wx = v.x; wy = v.y;
              }
              loaded = true;
            }
            wx ^= px; wy ^= py;
            l = row_low(wx, wy, lane);
            if (l < 0) break;                // unreachable for uncleared rows
            int old = 0;
            if (lane == 0) old = atomicMin(&spiv[l], r);
            old = __shfl(old, 0);
            if (old > r) {                   // claimed: publish row, queue evictee
              if (lane < 36) {
                ulonglong2 v; v.x = wx; v.y = wy;
                *(ulonglong2*)&g_rows[(size_t)r * TW + 2 * lane] = v;
              }
              if (lane == 0) lowA[r] = l;
              if (old != INF_I) { if (lane == 0) tailq[tl & 63] = old; tl++; }
              break;
            }
            // old < r: lost claim; keep chaining through new owner
          }
        }
      }
      __syncthreads();
      break;
    }

    if (tid == 0) { cnts[nxt] = 0; workIdx = 0; }
    for (int i = tid; i < cnt; i += 1024) stamp[lists[cur][i]] = pass;
    __syncthreads();
    for (;;) {
      int idx = 0;
      if (lane == 0) idx = atomicAdd(&workIdx, 1);
      idx = __shfl(idx, 0);
      if (idx >= cnt) break;
      int r = lists[cur][idx];
      int l = lowA[r];                       // >= 0 for every listed row
      ull wx = 0, wy = 0;
      bool loaded = false, modified = false;
      for (;;) {
        int p = spiv[l];                     // p < r always
        // prefetch winner's row; discarded if stamped (torn reads never used)
        ull px = 0, py = 0;
        if (lane < 36) {
          ulonglong2 v = *(const ulonglong2*)&g_rows[(size_t)p * TW + 2 * lane];
          px = v.x; py = v.y;
        }
        if (stamp[p] == pass) {              // winner busy this pass -> retry next
          if (lane == 0) { int q = atomicAdd(&cnts[nxt], 1); lists[nxt][q] = r; }
          break;
        }
        if (!loaded) {
          if (lane < 36) {
            ulonglong2 v = *(const ulonglong2*)&g_rows[(size_t)r * TW + 2 * lane];
            wx = v.x; wy = v.y;
          }
          loaded = true;
        }
        wx ^= px; wy ^= py;
        modified = true;
        l = row_low(wx, wy, lane);
        if (lane == 0) lowA[r] = l;
        if (l < 0) break;                    // unreachable for uncleared rows
        int old = 0;
        if (lane == 0) old = atomicMin(&spiv[l], r);
        old = __shfl(old, 0);
        if (old > r) {                       // claimed; evictee reacts next pass
          if (old != INF_I && lane == 0) { int q = atomicAdd(&cnts[nxt], 1); lists[nxt][q] = old; }
          break;
        }
        // old < r: lost claim; keep chaining
      }
      if (modified && l >= 0 && lane < 36) {
        ulonglong2 v; v.x = wx; v.y = wy;
        *(ulonglong2*)&g_rows[(size_t)r * TW + 2 * lane] = v;
      }
    }
    __syncthreads();
    cnt = cnts[nxt];
    pass++;
  }

  // epilogue: pair (edge rank nE-1-r, tri rank nT-1-l); loss1 = sum - max
  float sum = 0.f, mx = 0.f;
  for (int l = tid; l < nT; l += 1024) {
    int r = spiv[l];
    if (r != INF_I) {
      float len = g_ef[nE - 1 - r] - g_tf[nT - 1 - l];
      sum += len;
      mx = fmaxf(mx, len);
    }
  }
  #pragma unroll
  for (int off = 32; off; off >>= 1) {
    sum += __shfl_xor(sum, off, 64);
    mx = fmaxf(mx, __shfl_xor(mx, off, 64));
  }
  if (lane == 0) { ssum[wave] = sum; smax[wave] = mx; }
  __syncthreads();
  if (tid == 0) {
    float S = 0.f, M = 0.f;
    for (int i = 0; i < 16; ++i) { S += ssum[i]; M = fmaxf(M, smax[i]); }
    out[0] = g_loss0 + S - M;
  }
}

extern "C" void kernel_launch(void* const* d_in, const int* in_sizes, int n_in,
                              void* d_out, int out_size, void* d_ws, size_t ws_size,
                              hipStream_t stream) {
  const float* beta = (const float*)d_in[0];
  const int*   sv   = (const int*)d_in[1];
  const int*   sd   = (const int*)d_in[2];
  const int*   bf   = (const int*)d_in[4];
  float* out = (float*)d_out;

  int nV = in_sizes[0];
  int nS = in_sizes[2];

  k_main1<<<RB_E + RB_T + 1 + RB_C, 256, 0, stream>>>(beta, sv, sd, nV, nS);
  k_scat<<<TBLK + 1, 256, 0, stream>>>(bf, sd, nV, nS);
  k_reduce<<<1, 1024, 0, stream>>>(sd, nV, nS, out);
}